// Round 7
// baseline (281.512 us; speedup 1.0000x reference)
//
#include <hip/hip_runtime.h>
#include <math.h>

// Problem constants: B=64, MAX_H=64, MAX_W=32, D=512, S=8, HID=64
#define NB    64
#define MAXH  64
#define MAXW  32
#define DCH   512
#define SS    8
#define HID   64

#define QTOTAL ((size_t)NB * MAXH * MAXW * DCH)   // 67,108,864 floats

typedef float f4  __attribute__((ext_vector_type(4)));
typedef short s8v __attribute__((ext_vector_type(8)));   // 8 bf16 (4 VGPRs)

__device__ __forceinline__ float gelu_exact(float x) {
    // jax.nn.gelu(approximate=False): x * 0.5 * (1 + erf(x/sqrt(2)))
    return 0.5f * x * (1.0f + erff(x * 0.70710678118654752440f));
}

__device__ __forceinline__ unsigned short bf16_rne(float x) {
    unsigned int u = __float_as_uint(x);
    unsigned int r = u + 0x7fffu + ((u >> 16) & 1u);
    return (unsigned short)(r >> 16);
}

// ---------------------------------------------------------------------------
// Prep: w2 (64x512 f32) -> bf16 table in MFMA B-fragment order (64 KB, d_ws).
// 16x16x32 bf16 MFMA: lane l holds B[k=(l>>4)*8+j][n=l&15], j=0..7.
// Entry (kh, ct, lane): k = 32*kh + (l>>4)*8 + j, c = 16*ct + (l&15).
// ---------------------------------------------------------------------------
__global__ __launch_bounds__(256) void w2prep_kernel(
    const float* __restrict__ w2, s8v* __restrict__ w2b)
{
    const int tid  = blockIdx.x * 256 + threadIdx.x;   // 0..4095
    const int lane = tid & 63;
    const int ct   = (tid >> 6) & 31;
    const int kh   = tid >> 11;                        // 0..1
    const int q    = lane >> 4;
    const int m    = lane & 15;
    const int c    = ct * 16 + m;
    union { s8v v; unsigned short us[8]; } pk;
    #pragma unroll
    for (int j = 0; j < 8; ++j) {
        const int k = kh * 32 + q * 8 + j;
        pk.us[j] = bf16_rne(w2[k * DCH + c]);
    }
    w2b[tid] = pk.v;
}

// ---------------------------------------------------------------------------
// Main: one block = (b, i, half) -> 16 j x 512 c. Everything (delta GEMV AND
// bilinear) is MFMA: 3 x mfma_f32_16x16x32_bf16 per 16x16 tile.
//   MFMA 1,2: delta = h(16x64) @ w2(64x512)   (B from global w2b table)
//   MFMA 3:   bil   = a(16x8)  @ ri(8x512)    (B staged in LDS B-frag order;
//             a = per-row bilinear x-weights, 2 nonzeros/row; K padded to 32)
// C seeded with b2. Mask applied at store (skipped wave-uniformly when the
// whole half is active).
// ---------------------------------------------------------------------------
__global__ __launch_bounds__(256) void hgqg_kernel(
    const float* __restrict__ canonical,  // (8,8,512)
    const float* __restrict__ w1,         // (2,64)
    const float* __restrict__ b1,         // (64,)
    const s8v*   __restrict__ w2b,        // B-frag bf16 table (d_ws)
    const float* __restrict__ b2,         // (512,)
    const int*   __restrict__ hlist,      // (64,)
    const int*   __restrict__ wlist,      // (64,)
    float* __restrict__ out)              // queries flat, then mask flat
{
    // bijective swizzle (R5): spreads (b,i) across CUs
    const int raw  = blockIdx.x;                 // 0..8191
    const int id   = (raw ^ (raw >> 7)) & 8191;
    const int i    = id & 63;
    const int half = (id >> 6) & 1;
    const int b    = id >> 7;
    const int blk  = (b << 6) | i;
    const int t    = threadIdx.x;

    int H = hlist[b]; H = min(max(H, 1), MAXH);
    int W = wlist[b]; W = min(max(W, 1), MAXW);

    const int jbase = half << 4;                 // 0 or 16

    f4* q4 = (f4*)(out + (size_t)blk * (MAXW * DCH)) + jbase * 128;

    if (half == 0 && t < MAXW) {
        out[QTOTAL + (size_t)blk * MAXW + t] = (i < H && t < W) ? 1.0f : 0.0f;
    }

    const f4 z = {0.f, 0.f, 0.f, 0.f};

    if (i >= H || jbase >= W) {
        #pragma unroll
        for (int r = 0; r < 8; ++r) q4[t + r * 256] = z;
        return;
    }

    // ---- per-row uniforms ----
    const float u    = (H > 1) ? (float)i / (float)(H - 1) : 0.0f;
    const float sy   = fminf(u * 7.0f, 7.0f);
    const int   y0   = (int)sy;
    const int   y1   = min(y0 + 1, SS - 1);
    const float wy   = sy - (float)y0;
    const float winv = (W > 1) ? 1.0f / (float)(W - 1) : 0.0f;

    // ---- stage A: y-lerped canonical rows, bf16, B-fragment order (8 KB) ---
    // Entry e (== channel c): packs ri[x=0..7][c] as 8 bf16. Used as the
    // B operand rows k=0..7 by q==0 lanes; q>=1 lanes supply zeros.
    __shared__ __align__(16) s8v extb[512];
    #pragma unroll
    for (int ee = 0; ee < 2; ++ee) {
        const int e = t + ee * 256;       // channel c, coalesced per x
        union { s8v v; unsigned short us[8]; } pk;
        #pragma unroll
        for (int x = 0; x < 8; ++x) {
            const float a = canonical[(y0 * SS + x) * DCH + e];
            const float d = canonical[(y1 * SS + x) * DCH + e];
            pk.us[x] = bf16_rne(a + wy * (d - a));
        }
        extb[e] = pk.v;
    }

    // ---- stage B: hsh[jl][k] = gelu(u*w1[0][k] + v*w1[1][k] + b1[k]) ----
    __shared__ __align__(16) float hsh[16][68];
    {
        const int jl = t >> 4;              // 0..15
        const int k0 = (t & 15) * 4;        // 0..60
        const float v = (float)(jbase + jl) * winv;
        #pragma unroll
        for (int kk = 0; kk < 4; ++kk) {
            const int k = k0 + kk;
            hsh[jl][k] = gelu_exact(u * w1[k] + v * w1[HID + k] + b1[k]);
        }
    }
    __syncthreads();

    // ---- wave decomposition ----
    const int l = t & 63;          // lane
    const int w = t >> 6;          // wave 0..3 -> channels [w*128, w*128+128)
    const int q = l >> 4;          // quad
    const int m = l & 15;          // lane-in-quad

    // A-fragments (h): lane holds A[m][k=q*8+j] = hsh[m][q*8+j]
    union { s8v v; unsigned short us[8]; } A0, A1;
    {
        const float* hrow = &hsh[m][q * 8];
        #pragma unroll
        for (int j = 0; j < 8; ++j) {
            A0.us[j] = bf16_rne(hrow[j]);
            A1.us[j] = bf16_rne(hrow[32 + j]);
        }
    }

    // A-fragment (bilinear x-weights): q==0 lanes hold row m's weights over
    // x=0..7; all other lanes zero (k rows 8..31 of the K=32 ext MFMA).
    union { s8v v; unsigned short us[8]; } Ax;
    {
        float wloc[8];
        #pragma unroll
        for (int x = 0; x < 8; ++x) wloc[x] = 0.0f;
        const float v  = (float)(jbase + m) * winv;
        const float sx = fminf(v * 7.0f, 7.0f);
        const int   x0 = (int)sx;
        const int   x1 = min(x0 + 1, SS - 1);
        const float wx = sx - (float)x0;
        wloc[x0] += 1.0f - wx;
        wloc[x1] += wx;
        #pragma unroll
        for (int x = 0; x < 8; ++x)
            Ax.us[x] = (q == 0) ? bf16_rne(wloc[x]) : (unsigned short)0;
    }

    const bool fullhalf = (jbase + 16 <= W);   // wave-uniform
    const size_t obase = (size_t)blk * (MAXW * DCH) + (size_t)jbase * DCH;
    const s8v zs = {0, 0, 0, 0, 0, 0, 0, 0};

    #pragma unroll
    for (int tt = 0; tt < 8; ++tt) {
        const int ct = w * 8 + tt;           // c-tile 0..31
        const int c  = ct * 16 + m;          // this lane's channel (C/D col)

        // seed C with b2 (all 4 rows share the column's bias)
        const float bb2 = b2[c];
        f4 acc;
        acc[0] = bb2; acc[1] = bb2; acc[2] = bb2; acc[3] = bb2;

        // B operands: delta halves from global table, bilinear rows from LDS
        const s8v b0  = w2b[ct * 64 + l];
        const s8v b1f = w2b[2048 + ct * 64 + l];
        s8v be = zs;
        if (q == 0) be = extb[c];            // B[k=j][n=m] = ri[j][c]

        acc = __builtin_amdgcn_mfma_f32_16x16x32_bf16(A0.v, b0,  acc, 0, 0, 0);
        acc = __builtin_amdgcn_mfma_f32_16x16x32_bf16(A1.v, b1f, acc, 0, 0, 0);
        acc = __builtin_amdgcn_mfma_f32_16x16x32_bf16(Ax.v, be,  acc, 0, 0, 0);

        // store (C layout: col = m, row = q*4 + r); mask only boundary halves
        if (fullhalf) {
            #pragma unroll
            for (int r = 0; r < 4; ++r)
                out[obase + (size_t)(q * 4 + r) * DCH + c] = acc[r];
        } else {
            #pragma unroll
            for (int r = 0; r < 4; ++r) {
                const int j = jbase + q * 4 + r;
                out[obase + (size_t)(q * 4 + r) * DCH + c] = (j < W) ? acc[r] : 0.0f;
            }
        }
    }
}

extern "C" void kernel_launch(void* const* d_in, const int* in_sizes, int n_in,
                              void* d_out, int out_size, void* d_ws, size_t ws_size,
                              hipStream_t stream) {
    const float* canonical = (const float*)d_in[0];
    const float* w1        = (const float*)d_in[1];
    const float* b1        = (const float*)d_in[2];
    const float* w2        = (const float*)d_in[3];
    const float* b2        = (const float*)d_in[4];
    const int*   hlist     = (const int*)d_in[6];
    const int*   wlist     = (const int*)d_in[7];
    float* out = (float*)d_out;
    s8v*   w2b = (s8v*)d_ws;   // 64 KB bf16 B-fragment table

    w2prep_kernel<<<16, 256, 0, stream>>>(w2, w2b);
    hgqg_kernel<<<2 * NB * MAXH, 256, 0, stream>>>(
        canonical, w1, b1, w2b, b2, hlist, wlist, out);
}